// Round 2
// baseline (282.492 us; speedup 1.0000x reference)
//
#include <hip/hip_runtime.h>

// Native 4-wide float vector (works with __builtin_nontemporal_store,
// lowers to global_load/store_dwordx4).
typedef float f4 __attribute__((ext_vector_type(4)));

// Problem constants (from reference)
constexpr int OUTP = 32;        // OUT_PLANES
constexpr int INP  = 16;        // IN_PLANES
constexpr int REPS = 16;        // REP = 256/16
constexpr int BB   = 8;
constexpr int HW   = 32 * 32;   // 1024 pixels
constexpr int P4   = HW / 4;    // 256 float4 per channel
constexpr size_t OUT1_F4 = (size_t)BB * OUTP * INP * REPS * P4;  // 16777216 f4

// Fused kernel:
//   blocks [0, 512):   out1 path. block -> (b, i, pixel-chunk). 64 threads,
//                      each thread owns one f4 pixel group, 16 r-channels
//                      in registers, loops over 32 output planes.
//   blocks [512,1536): out2 path. one thread per out2 f4.
__global__ __launch_bounds__(64) void qconv_pw_fused(
    const f4* __restrict__ x,      // (B, 256, H, W) as f4: (b*256+c)*P4 + v
    const f4* __restrict__ x2,     // (B, 16, H, W)
    const float* __restrict__ w,   // (512,) == w2[o][i] at w[o*16+i]
    f4* __restrict__ out)          // out1 (B,8192,H,W) then relu_out2 (B,32,H,W)
{
    const int blk = blockIdx.x;
    const int tid = threadIdx.x;

    if (blk < 512) {
        // ---- out1 path ----
        const int chunk = blk & 3;          // which 64-f4 chunk of the 256
        const int bi    = blk >> 2;
        const int b     = bi >> 4;
        const int i     = bi & 15;
        const int v     = chunk * 64 + tid; // f4 pixel index in [0,256)

        // Load the 16 repeated input channels for this (b, i) group.
        const f4* xbase = x + (size_t)(b * 256 + i * REPS) * P4 + v;
        f4 xv[REPS];
#pragma unroll
        for (int r = 0; r < REPS; ++r) {
            xv[r] = xbase[(size_t)r * P4];
        }

        // Segment sum S[b,i,p] = sum_r x[b, i*16+r, p]
        f4 S = (f4)(0.f);
#pragma unroll
        for (int r = 0; r < REPS; ++r) {
            S += xv[r];
        }

        for (int o = 0; o < OUTP; ++o) {
            const float wo = w[o * INP + i];   // wave-uniform -> scalar load
            // gated weight: w * (w*S > 0), per pixel component
            f4 gw;
            gw.x = (wo * S.x > 0.f) ? wo : 0.f;
            gw.y = (wo * S.y > 0.f) ? wo : 0.f;
            gw.z = (wo * S.z > 0.f) ? wo : 0.f;
            gw.w = (wo * S.w > 0.f) ? wo : 0.f;

            // flat f4 index: (b*8192 + o*256 + i*16 + r)*256 + v
            const size_t base = (size_t)((b * OUTP + o) * INP + i) * REPS * P4 + v;
#pragma unroll
            for (int r = 0; r < REPS; ++r) {
                f4 res = xv[r] * gw;
                __builtin_nontemporal_store(res, &out[base + (size_t)r * P4]);
            }
        }
    } else {
        // ---- relu_out2 path ----
        const int t    = (blk - 512) * 64 + tid;   // [0, 65536)
        const int v    = t & (P4 - 1);             // f4 pixel index
        const int rest = t >> 8;                   // [0, 256) = B*OUTP
        const int o    = rest & (OUTP - 1);
        const int b    = rest >> 5;

        const f4* xb = x2 + (size_t)(b * INP) * P4 + v;
        f4 acc = (f4)(0.f);
#pragma unroll
        for (int i = 0; i < INP; ++i) {
            const float wo = w[o * INP + i];       // wave-uniform -> scalar load
            acc += xb[(size_t)i * P4] * wo;
        }
        acc.x = fmaxf(acc.x, 0.f);
        acc.y = fmaxf(acc.y, 0.f);
        acc.z = fmaxf(acc.z, 0.f);
        acc.w = fmaxf(acc.w, 0.f);

        const size_t oidx = OUT1_F4 + (size_t)(b * OUTP + o) * P4 + v;
        __builtin_nontemporal_store(acc, &out[oidx]);
    }
}

extern "C" void kernel_launch(void* const* d_in, const int* in_sizes, int n_in,
                              void* d_out, int out_size, void* d_ws, size_t ws_size,
                              hipStream_t stream) {
    const f4* x  = (const f4*)d_in[0];   // (8, 256, 32, 32) fp32
    const f4* x2 = (const f4*)d_in[1];   // (8, 16, 32, 32) fp32
    const float* w = (const float*)d_in[2]; // (512,1,1,1) fp32
    f4* out = (f4*)d_out;

    const int grid = 512 + 1024;  // out1 blocks + out2 blocks
    qconv_pw_fused<<<grid, 64, 0, stream>>>(x, x2, w, out);
}

// Round 3
// 271.260 us; speedup vs baseline: 1.0414x; 1.0414x over previous
//
#include <hip/hip_runtime.h>

// Native 4-wide float vector (works with plain & nontemporal stores,
// lowers to global_load/store_dwordx4).
typedef float f4 __attribute__((ext_vector_type(4)));

// Problem constants (from reference)
constexpr int OUTP = 32;        // OUT_PLANES
constexpr int INP  = 16;        // IN_PLANES
constexpr int REPS = 16;        // REP = 256/16
constexpr int BB   = 8;
constexpr int HW   = 32 * 32;   // 1024 pixels
constexpr int P4   = HW / 4;    // 256 f4 per channel
constexpr size_t OUT1_F4 = (size_t)BB * OUTP * INP * REPS * P4;  // 16777216 f4

// Fused kernel, block = 1024 threads (16 waves):
//   blocks [0, 512):  out1. block -> (b, i, 64-f4 pixel chunk); thread ->
//                     (r = tid>>6, lane = tid&63). LDS tree-reduce over r
//                     gives S[b,i,pixel]; then each thread stores 32 o-planes.
//                     8192 waves total = 32 waves/CU -> saturates write BW.
//   blocks [512,576): out2. one thread per out2 f4 (65536 threads).
__global__ __launch_bounds__(1024) void qconv_pw_fused(
    const f4* __restrict__ x,      // (B, 256, H, W) as f4: (b*256+c)*P4 + v
    const f4* __restrict__ x2,     // (B, 16, H, W)
    const float* __restrict__ w,   // (512,) == w2[o][i] at w[o*16+i]
    f4* __restrict__ out)          // out1 (B,8192,H,W) then relu_out2 (B,32,H,W)
{
    __shared__ f4 lds[REPS][64];   // 16 KiB

    const int blk = blockIdx.x;
    const int tid = threadIdx.x;

    if (blk < 512) {
        // ---- out1 path ----
        const int chunk = blk & 3;          // which 64-f4 chunk of the 256
        const int bi    = blk >> 2;
        const int b     = bi >> 4;
        const int i     = bi & 15;
        const int r     = tid >> 6;         // repeat index 0..15 (wave-uniform)
        const int lane  = tid & 63;
        const int v     = chunk * 64 + lane; // f4 pixel index in [0,256)

        // One x value per thread: x[b, i*16+r, pixel v]
        const f4 xv = x[(size_t)(b * 256 + i * REPS + r) * P4 + v];

        // Segment sum S[b,i,p] = sum_r x[b,i*16+r,p] via LDS tree over r.
        lds[r][lane] = xv;
        __syncthreads();
        f4 S = xv;
#pragma unroll
        for (int k = 8; k >= 1; k >>= 1) {
            if (r < k) { S += lds[r + k][lane]; lds[r][lane] = S; }
            __syncthreads();
        }
        S = lds[0][lane];

        // flat f4 index: ((b*32+o)*16+i)*16+r)*256 + v ; o-stride = 65536 f4
        const size_t base0 = (size_t)(((b * OUTP) * INP + i) * REPS + r) * P4 + v;
#pragma unroll
        for (int o = 0; o < OUTP; ++o) {
            const float wo = w[o * INP + i];   // wave-uniform -> scalar load
            f4 res;
            res.x = (wo * S.x > 0.f) ? xv.x * wo : 0.f;
            res.y = (wo * S.y > 0.f) ? xv.y * wo : 0.f;
            res.z = (wo * S.z > 0.f) ? xv.z * wo : 0.f;
            res.w = (wo * S.w > 0.f) ? xv.w * wo : 0.f;
            out[base0 + (size_t)o * (INP * REPS * P4)] = res;
        }
    } else {
        // ---- relu_out2 path ----
        const int t    = (blk - 512) * 1024 + tid; // [0, 65536)
        const int v    = t & (P4 - 1);             // f4 pixel index
        const int rest = t >> 8;                   // [0, 256) = B*OUTP
        const int o    = rest & (OUTP - 1);
        const int b    = rest >> 5;

        const f4* xb = x2 + (size_t)(b * INP) * P4 + v;
        f4 acc = (f4)(0.f);
#pragma unroll
        for (int i = 0; i < INP; ++i) {
            const float wo = w[o * INP + i];       // wave-uniform -> scalar load
            acc += xb[(size_t)i * P4] * wo;
        }
        acc.x = fmaxf(acc.x, 0.f);
        acc.y = fmaxf(acc.y, 0.f);
        acc.z = fmaxf(acc.z, 0.f);
        acc.w = fmaxf(acc.w, 0.f);

        out[OUT1_F4 + (size_t)(b * OUTP + o) * P4 + v] = acc;
    }
}

extern "C" void kernel_launch(void* const* d_in, const int* in_sizes, int n_in,
                              void* d_out, int out_size, void* d_ws, size_t ws_size,
                              hipStream_t stream) {
    const f4* x  = (const f4*)d_in[0];      // (8, 256, 32, 32) fp32
    const f4* x2 = (const f4*)d_in[1];      // (8, 16, 32, 32) fp32
    const float* w = (const float*)d_in[2]; // (512,1,1,1) fp32
    f4* out = (f4*)d_out;

    const int grid = 512 + 64;  // out1 blocks + out2 blocks
    qconv_pw_fused<<<grid, 1024, 0, stream>>>(x, x2, w, out);
}